// Round 1
// baseline (251.252 us; speedup 1.0000x reference)
//
#include <hip/hip_runtime.h>

#define H_IN 448
#define W_IN 448
#define HW_IN (H_IN * W_IN)
#define BGW 488
#define BGHW (BGW * BGW)
#define OUTI 256
#define OUTI_PIX (OUTI * OUTI)
#define OUTM 64
#define B_SAMPLES 64

__device__ __forceinline__ float clamp01(float x) { return fminf(fmaxf(x, 0.f), 1.f); }
__device__ __forceinline__ int clampi(int x, int lo, int hi) { return min(max(x, lo), hi); }

// ---------------- K1: per-sample mask bounding box ----------------
__global__ void k_bbox(const float* __restrict__ ms, int* __restrict__ bbox) {
    int b = blockIdx.x;
    const float4* m4 = (const float4*)(ms + (size_t)b * HW_IN);
    int miny = H_IN, maxy = -1, minx = W_IN, maxx = -1;
    for (int i = threadIdx.x; i < HW_IN / 4; i += blockDim.x) {
        float4 v = m4[i];
        bool a0 = v.x > 0.5f, a1 = v.y > 0.5f, a2 = v.z > 0.5f, a3 = v.w > 0.5f;
        if (a0 | a1 | a2 | a3) {
            int y = i / (W_IN / 4);
            int xb = (i % (W_IN / 4)) * 4;
            miny = min(miny, y); maxy = max(maxy, y);
            if (a0) { minx = min(minx, xb);     maxx = max(maxx, xb); }
            if (a1) { minx = min(minx, xb + 1); maxx = max(maxx, xb + 1); }
            if (a2) { minx = min(minx, xb + 2); maxx = max(maxx, xb + 2); }
            if (a3) { minx = min(minx, xb + 3); maxx = max(maxx, xb + 3); }
        }
    }
    __shared__ int s[4];
    if (threadIdx.x == 0) { s[0] = H_IN; s[1] = -1; s[2] = W_IN; s[3] = -1; }
    __syncthreads();
    atomicMin(&s[0], miny); atomicMax(&s[1], maxy);
    atomicMin(&s[2], minx); atomicMax(&s[3], maxx);
    __syncthreads();
    if (threadIdx.x < 4) bbox[b * 4 + threadIdx.x] = s[threadIdx.x];
}

// Shared geometry helper: load per-sample params
struct Geo {
    int miny, minx, h, w, top, left, Hp, Wp;
};
__device__ __forceinline__ Geo load_geo(const int* __restrict__ bbox,
                                        const int* __restrict__ pads, int b) {
    Geo g;
    g.miny = bbox[b * 4 + 0];
    int maxy = bbox[b * 4 + 1];
    g.minx = bbox[b * 4 + 2];
    int maxx = bbox[b * 4 + 3];
    int left = pads[b * 4 + 0], right = pads[b * 4 + 1];
    int top = pads[b * 4 + 2], bot = pads[b * 4 + 3];
    g.h = maxy - g.miny + 1;
    g.w = maxx - g.minx + 1;
    g.top = top; g.left = left;
    g.Hp = g.h + top + bot;
    g.Wp = g.w + left + right;
    return g;
}

// _src_coords: t = clip((i+0.5)*(sizef/n)-0.5, 0, sizef-1); t0=floor; t1=min(t0+1,size-1)
__device__ __forceinline__ void src_coord(int i, int n_out, int size,
                                          int& t0, int& t1, float& frac) {
    float sizef = (float)size;
    float t = (i + 0.5f) * (sizef / (float)n_out) - 0.5f;
    t = fminf(fmaxf(t, 0.f), sizef - 1.f);
    t0 = (int)floorf(t);
    t1 = min(t0 + 1, size - 1);
    frac = t - (float)t0;
}

// ---------------- K2: bilinear resize of composited image + brightness ----------------
__global__ void k_resize_img(const float* __restrict__ img, const float* __restrict__ ms,
                             const float* __restrict__ bg, const int* __restrict__ pads,
                             const int* __restrict__ csel, const float* __restrict__ rcol,
                             const float* __restrict__ jit, const int* __restrict__ bbox,
                             float* __restrict__ out) {
    int b = blockIdx.y;
    int pix = blockIdx.x * blockDim.x + threadIdx.x;  // 0..65535
    int oy = pix >> 8, ox = pix & 255;

    Geo g = load_geo(bbox, pads, b);
    bool useBg = csel[b] > 2;
    float c0 = rcol[b * 3 + 0], c1 = rcol[b * 3 + 1], c2 = rcol[b * 3 + 2];
    float bfac = 0.9f + 0.2f * jit[b * 4 + 0];

    int y0, y1, x0, x1; float wy, wx;
    src_coord(oy, OUTI, g.Hp, y0, y1, wy);
    src_coord(ox, OUTI, g.Wp, x0, x1, wx);

    const float* imB = img + (size_t)b * 3 * HW_IN;
    const float* msB = ms + (size_t)b * HW_IN;
    const float* bgB = bg + (size_t)b * 3 * BGHW;

    float acc0 = 0.f, acc1 = 0.f, acc2 = 0.f;
#pragma unroll
    for (int tap = 0; tap < 4; ++tap) {
        int P = (tap & 2) ? y1 : y0;
        int Q = (tap & 1) ? x1 : x0;
        float wgt = ((tap & 2) ? wy : 1.f - wy) * ((tap & 1) ? wx : 1.f - wx);
        bool in_crop = (P >= g.top) && (P < g.top + g.h) && (Q >= g.left) && (Q < g.left + g.w);
        int r = clampi(g.miny + P - g.top, 0, H_IN - 1);
        int c = clampi(g.minx + Q - g.left, 0, W_IN - 1);
        bool mm = in_crop && (msB[r * W_IN + c] > 0.5f);
        float v0, v1, v2;
        if (mm) {
            int o = r * W_IN + c;
            v0 = imB[o]; v1 = imB[HW_IN + o]; v2 = imB[2 * HW_IN + o];
        } else if (useBg) {
            int Pc = clampi(P, 0, BGW - 1), Qc = clampi(Q, 0, BGW - 1);
            int o = Pc * BGW + Qc;
            v0 = bgB[o]; v1 = bgB[BGHW + o]; v2 = bgB[2 * BGHW + o];
        } else {
            v0 = c0; v1 = c1; v2 = c2;
        }
        acc0 += wgt * v0; acc1 += wgt * v1; acc2 += wgt * v2;
    }
    size_t o = (size_t)b * 3 * OUTI_PIX + pix;
    out[o] = clamp01(acc0 * bfac);
    out[o + OUTI_PIX] = clamp01(acc1 * bfac);
    out[o + 2 * OUTI_PIX] = clamp01(acc2 * bfac);
}

// ---------------- K2b: bilinear resize of mask to 64x64 ----------------
__global__ void k_resize_msk(const float* __restrict__ ms, const int* __restrict__ pads,
                             const int* __restrict__ bbox, float* __restrict__ outm) {
    int b = blockIdx.y;
    int pix = blockIdx.x * blockDim.x + threadIdx.x;  // 0..4095
    int oy = pix >> 6, ox = pix & 63;

    Geo g = load_geo(bbox, pads, b);
    int y0, y1, x0, x1; float wy, wx;
    src_coord(oy, OUTM, g.Hp, y0, y1, wy);
    src_coord(ox, OUTM, g.Wp, x0, x1, wx);

    const float* msB = ms + (size_t)b * HW_IN;
    float acc = 0.f;
#pragma unroll
    for (int tap = 0; tap < 4; ++tap) {
        int P = (tap & 2) ? y1 : y0;
        int Q = (tap & 1) ? x1 : x0;
        float wgt = ((tap & 2) ? wy : 1.f - wy) * ((tap & 1) ? wx : 1.f - wx);
        bool in_crop = (P >= g.top) && (P < g.top + g.h) && (Q >= g.left) && (Q < g.left + g.w);
        int r = clampi(g.miny + P - g.top, 0, H_IN - 1);
        int c = clampi(g.minx + Q - g.left, 0, W_IN - 1);
        bool mm = in_crop && (msB[r * W_IN + c] > 0.5f);
        acc += wgt * (mm ? 1.f : 0.f);
    }
    outm[(size_t)b * (OUTM * OUTM) + pix] = acc;
}

// ---------------- K3: per-sample mean of gray over the brightness-adjusted image ----------------
__global__ void k_gray_mean(const float* __restrict__ img_out, float* __restrict__ means) {
    int b = blockIdx.x;
    const float* p = img_out + (size_t)b * 3 * OUTI_PIX;
    const float4* r4 = (const float4*)p;
    const float4* g4 = (const float4*)(p + OUTI_PIX);
    const float4* b4 = (const float4*)(p + 2 * OUTI_PIX);
    float s = 0.f;
    for (int i = threadIdx.x; i < OUTI_PIX / 4; i += blockDim.x) {
        float4 r = r4[i], g = g4[i], bl = b4[i];
        s += 0.299f * r.x + 0.587f * g.x + 0.114f * bl.x;
        s += 0.299f * r.y + 0.587f * g.y + 0.114f * bl.y;
        s += 0.299f * r.z + 0.587f * g.z + 0.114f * bl.z;
        s += 0.299f * r.w + 0.587f * g.w + 0.114f * bl.w;
    }
#pragma unroll
    for (int off = 32; off > 0; off >>= 1) s += __shfl_down(s, off, 64);
    __shared__ float ls[4];
    int wid = threadIdx.x >> 6, lane = threadIdx.x & 63;
    if (lane == 0) ls[wid] = s;
    __syncthreads();
    if (threadIdx.x == 0) means[b] = (ls[0] + ls[1] + ls[2] + ls[3]) * (1.f / (float)OUTI_PIX);
}

// ---------------- K4: contrast + saturation + hue jitter (in place) ----------------
__global__ void k_jitter(float* __restrict__ io, const float* __restrict__ jit,
                         const float* __restrict__ means) {
    int b = blockIdx.y;
    int pix = blockIdx.x * blockDim.x + threadIdx.x;
    float cc = 0.9f + 0.2f * jit[b * 4 + 1];
    float ssf = 0.9f + 0.2f * jit[b * 4 + 2];
    float hd = -0.1f + 0.2f * jit[b * 4 + 3];
    float mean = means[b];
    float* p = io + (size_t)b * 3 * OUTI_PIX + pix;
    float r = p[0], g = p[OUTI_PIX], bl = p[2 * OUTI_PIX];
    // contrast
    r = clamp01(cc * r + (1.f - cc) * mean);
    g = clamp01(cc * g + (1.f - cc) * mean);
    bl = clamp01(cc * bl + (1.f - cc) * mean);
    // saturation
    float gray = 0.299f * r + 0.587f * g + 0.114f * bl;
    r = clamp01(ssf * r + (1.f - ssf) * gray);
    g = clamp01(ssf * g + (1.f - ssf) * gray);
    bl = clamp01(ssf * bl + (1.f - ssf) * gray);
    // rgb -> hsv
    float mx = fmaxf(r, fmaxf(g, bl));
    float mn = fminf(r, fminf(g, bl));
    float d = mx - mn;
    float dsv = (d > 0.f) ? d : 1.f;
    float hch;
    if (mx == r) {
        float t = (g - bl) / dsv;
        t = fmodf(t, 6.f);
        if (t < 0.f) t += 6.f;
        hch = t;
    } else if (mx == g) {
        hch = (bl - r) / dsv + 2.f;
    } else {
        hch = (r - g) / dsv + 4.f;
    }
    hch = (d > 0.f) ? hch * (1.f / 6.f) : 0.f;
    float sat = (mx > 0.f) ? d / mx : 0.f;
    float v = mx;
    // hue shift, mod 1
    float hh = hch + hd;
    hh -= floorf(hh);
    // hsv -> rgb
    float h6 = hh * 6.f;
    float fi = floorf(h6);
    float f = h6 - fi;
    float pp = v * (1.f - sat);
    float q = v * (1.f - f * sat);
    float t = v * (1.f - (1.f - f) * sat);
    int im = ((int)fi) % 6;
    float ro, go, bo;
    switch (im) {
        case 0: ro = v;  go = t;  bo = pp; break;
        case 1: ro = q;  go = v;  bo = pp; break;
        case 2: ro = pp; go = v;  bo = t;  break;
        case 3: ro = pp; go = q;  bo = v;  break;
        case 4: ro = t;  go = pp; bo = v;  break;
        default: ro = v; go = pp; bo = q;  break;
    }
    p[0] = clamp01(ro);
    p[OUTI_PIX] = clamp01(go);
    p[2 * OUTI_PIX] = clamp01(bo);
}

extern "C" void kernel_launch(void* const* d_in, const int* in_sizes, int n_in,
                              void* d_out, int out_size, void* d_ws, size_t ws_size,
                              hipStream_t stream) {
    const float* img = (const float*)d_in[0];
    const float* ms = (const float*)d_in[1];
    const float* bg = (const float*)d_in[2];
    const int* pads = (const int*)d_in[3];
    const int* csel = (const int*)d_in[4];
    const float* rcol = (const float*)d_in[5];
    const float* jit = (const float*)d_in[6];
    float* out = (float*)d_out;

    int* bbox = (int*)d_ws;
    float* means = (float*)((char*)d_ws + B_SAMPLES * 4 * sizeof(int));
    float* outm = out + (size_t)B_SAMPLES * 3 * OUTI_PIX;

    k_bbox<<<B_SAMPLES, 256, 0, stream>>>(ms, bbox);
    k_resize_img<<<dim3(OUTI_PIX / 256, B_SAMPLES), 256, 0, stream>>>(
        img, ms, bg, pads, csel, rcol, jit, bbox, out);
    k_resize_msk<<<dim3((OUTM * OUTM) / 256, B_SAMPLES), 256, 0, stream>>>(ms, pads, bbox, outm);
    k_gray_mean<<<B_SAMPLES, 256, 0, stream>>>(out, means);
    k_jitter<<<dim3(OUTI_PIX / 256, B_SAMPLES), 256, 0, stream>>>(out, jit, means);
}

// Round 2
// 140.468 us; speedup vs baseline: 1.7887x; 1.7887x over previous
//
#include <hip/hip_runtime.h>

#define H_IN 448
#define W_IN 448
#define HW_IN (H_IN * W_IN)
#define BGW 488
#define BGHW (BGW * BGW)
#define OUTI 256
#define OUTI_PIX (OUTI * OUTI)
#define OUTM 64
#define B_SAMPLES 64
#define BBOX_CHUNKS 16
#define BBOX_ROWS (H_IN / BBOX_CHUNKS)  // 28

__device__ __forceinline__ float clamp01(float x) { return fminf(fmaxf(x, 0.f), 1.f); }
__device__ __forceinline__ int clampi(int x, int lo, int hi) { return min(max(x, lo), hi); }

// ---------------- K1: per-sample mask bounding box (split across chunks) ----------------
// bbox layout per sample: [miny, -maxy, minx, -maxx], all combined via atomicMin.
// Init pattern 0x7F7F7F7F (large positive). Empty-chunk contributions (H, 1, W, 1)
// equal the reference's identity values (min->size, max->-1).
__global__ void k_bbox(const float* __restrict__ ms, int* __restrict__ bbox) {
    int b = blockIdx.y;
    int chunk = blockIdx.x;
    const float4* m4 = (const float4*)(ms + (size_t)b * HW_IN + (size_t)chunk * BBOX_ROWS * W_IN);
    int miny = H_IN, maxy = -1, minx = W_IN, maxx = -1;
    const int N4 = BBOX_ROWS * (W_IN / 4);  // 3136
    for (int i = threadIdx.x; i < N4; i += blockDim.x) {
        float4 v = m4[i];
        bool a0 = v.x > 0.5f, a1 = v.y > 0.5f, a2 = v.z > 0.5f, a3 = v.w > 0.5f;
        if (a0 | a1 | a2 | a3) {
            int y = chunk * BBOX_ROWS + i / (W_IN / 4);
            int xb = (i % (W_IN / 4)) * 4;
            miny = min(miny, y); maxy = max(maxy, y);
            if (a0) { minx = min(minx, xb);     maxx = max(maxx, xb); }
            if (a1) { minx = min(minx, xb + 1); maxx = max(maxx, xb + 1); }
            if (a2) { minx = min(minx, xb + 2); maxx = max(maxx, xb + 2); }
            if (a3) { minx = min(minx, xb + 3); maxx = max(maxx, xb + 3); }
        }
    }
    __shared__ int s[4];
    if (threadIdx.x == 0) { s[0] = H_IN; s[1] = -1; s[2] = W_IN; s[3] = -1; }
    __syncthreads();
    atomicMin(&s[0], miny); atomicMax(&s[1], maxy);
    atomicMin(&s[2], minx); atomicMax(&s[3], maxx);
    __syncthreads();
    if (threadIdx.x == 0) {
        atomicMin(&bbox[b * 4 + 0], s[0]);
        atomicMin(&bbox[b * 4 + 1], -s[1]);
        atomicMin(&bbox[b * 4 + 2], s[2]);
        atomicMin(&bbox[b * 4 + 3], -s[3]);
    }
}

// Shared geometry helper: load per-sample params
struct Geo {
    int miny, minx, h, w, top, left, Hp, Wp;
};
__device__ __forceinline__ Geo load_geo(const int* __restrict__ bbox,
                                        const int* __restrict__ pads, int b) {
    Geo g;
    g.miny = bbox[b * 4 + 0];
    int maxy = -bbox[b * 4 + 1];
    g.minx = bbox[b * 4 + 2];
    int maxx = -bbox[b * 4 + 3];
    int left = pads[b * 4 + 0], right = pads[b * 4 + 1];
    int top = pads[b * 4 + 2], bot = pads[b * 4 + 3];
    g.h = maxy - g.miny + 1;
    g.w = maxx - g.minx + 1;
    g.top = top; g.left = left;
    g.Hp = g.h + top + bot;
    g.Wp = g.w + left + right;
    return g;
}

// _src_coords: t = clip((i+0.5)*(sizef/n)-0.5, 0, sizef-1); t0=floor; t1=min(t0+1,size-1)
__device__ __forceinline__ void src_coord(int i, int n_out, int size,
                                          int& t0, int& t1, float& frac) {
    float sizef = (float)size;
    float t = (i + 0.5f) * (sizef / (float)n_out) - 0.5f;
    t = fminf(fmaxf(t, 0.f), sizef - 1.f);
    t0 = (int)floorf(t);
    t1 = min(t0 + 1, size - 1);
    frac = t - (float)t0;
}

// ---------------- K2: bilinear resize of composited image + brightness + gray partials ----
__global__ void k_resize_img(const float* __restrict__ img, const float* __restrict__ ms,
                             const float* __restrict__ bg, const int* __restrict__ pads,
                             const int* __restrict__ csel, const float* __restrict__ rcol,
                             const float* __restrict__ jit, const int* __restrict__ bbox,
                             float* __restrict__ out, float* __restrict__ partials) {
    int b = blockIdx.y;
    int pix = blockIdx.x * blockDim.x + threadIdx.x;  // 0..65535
    int oy = pix >> 8, ox = pix & 255;

    Geo g = load_geo(bbox, pads, b);
    bool useBg = csel[b] > 2;
    float c0 = rcol[b * 3 + 0], c1 = rcol[b * 3 + 1], c2 = rcol[b * 3 + 2];
    float bfac = 0.9f + 0.2f * jit[b * 4 + 0];

    int y0, y1, x0, x1; float wy, wx;
    src_coord(oy, OUTI, g.Hp, y0, y1, wy);
    src_coord(ox, OUTI, g.Wp, x0, x1, wx);

    const float* imB = img + (size_t)b * 3 * HW_IN;
    const float* msB = ms + (size_t)b * HW_IN;
    const float* bgB = bg + (size_t)b * 3 * BGHW;

    float acc0 = 0.f, acc1 = 0.f, acc2 = 0.f;
#pragma unroll
    for (int tap = 0; tap < 4; ++tap) {
        int P = (tap & 2) ? y1 : y0;
        int Q = (tap & 1) ? x1 : x0;
        float wgt = ((tap & 2) ? wy : 1.f - wy) * ((tap & 1) ? wx : 1.f - wx);
        bool in_crop = (P >= g.top) && (P < g.top + g.h) && (Q >= g.left) && (Q < g.left + g.w);
        int r = clampi(g.miny + P - g.top, 0, H_IN - 1);
        int c = clampi(g.minx + Q - g.left, 0, W_IN - 1);
        bool mm = in_crop && (msB[r * W_IN + c] > 0.5f);
        float v0, v1, v2;
        if (mm) {
            int o = r * W_IN + c;
            v0 = imB[o]; v1 = imB[HW_IN + o]; v2 = imB[2 * HW_IN + o];
        } else if (useBg) {
            int Pc = clampi(P, 0, BGW - 1), Qc = clampi(Q, 0, BGW - 1);
            int o = Pc * BGW + Qc;
            v0 = bgB[o]; v1 = bgB[BGHW + o]; v2 = bgB[2 * BGHW + o];
        } else {
            v0 = c0; v1 = c1; v2 = c2;
        }
        acc0 += wgt * v0; acc1 += wgt * v1; acc2 += wgt * v2;
    }
    float o0 = clamp01(acc0 * bfac);
    float o1 = clamp01(acc1 * bfac);
    float o2 = clamp01(acc2 * bfac);
    size_t o = (size_t)b * 3 * OUTI_PIX + pix;
    out[o] = o0;
    out[o + OUTI_PIX] = o1;
    out[o + 2 * OUTI_PIX] = o2;

    // deterministic per-block gray partial sum
    float gsum = 0.299f * o0 + 0.587f * o1 + 0.114f * o2;
#pragma unroll
    for (int off = 32; off > 0; off >>= 1) gsum += __shfl_down(gsum, off, 64);
    __shared__ float ls[4];
    int wid = threadIdx.x >> 6, lane = threadIdx.x & 63;
    if (lane == 0) ls[wid] = gsum;
    __syncthreads();
    if (threadIdx.x == 0)
        partials[b * 256 + blockIdx.x] = ls[0] + ls[1] + ls[2] + ls[3];
}

// ---------------- K2b: bilinear resize of mask to 64x64 ----------------
__global__ void k_resize_msk(const float* __restrict__ ms, const int* __restrict__ pads,
                             const int* __restrict__ bbox, float* __restrict__ outm) {
    int b = blockIdx.y;
    int pix = blockIdx.x * blockDim.x + threadIdx.x;  // 0..4095
    int oy = pix >> 6, ox = pix & 63;

    Geo g = load_geo(bbox, pads, b);
    int y0, y1, x0, x1; float wy, wx;
    src_coord(oy, OUTM, g.Hp, y0, y1, wy);
    src_coord(ox, OUTM, g.Wp, x0, x1, wx);

    const float* msB = ms + (size_t)b * HW_IN;
    float acc = 0.f;
#pragma unroll
    for (int tap = 0; tap < 4; ++tap) {
        int P = (tap & 2) ? y1 : y0;
        int Q = (tap & 1) ? x1 : x0;
        float wgt = ((tap & 2) ? wy : 1.f - wy) * ((tap & 1) ? wx : 1.f - wx);
        bool in_crop = (P >= g.top) && (P < g.top + g.h) && (Q >= g.left) && (Q < g.left + g.w);
        int r = clampi(g.miny + P - g.top, 0, H_IN - 1);
        int c = clampi(g.minx + Q - g.left, 0, W_IN - 1);
        bool mm = in_crop && (msB[r * W_IN + c] > 0.5f);
        acc += wgt * (mm ? 1.f : 0.f);
    }
    outm[(size_t)b * (OUTM * OUTM) + pix] = acc;
}

// ---------------- K3: contrast + saturation + hue jitter (in place, 4 px/thread) --------
__device__ __forceinline__ void jitter_px(float& r, float& g, float& bl,
                                          float cc, float ssf, float hd, float mean) {
    // contrast
    r = clamp01(cc * r + (1.f - cc) * mean);
    g = clamp01(cc * g + (1.f - cc) * mean);
    bl = clamp01(cc * bl + (1.f - cc) * mean);
    // saturation
    float gray = 0.299f * r + 0.587f * g + 0.114f * bl;
    r = clamp01(ssf * r + (1.f - ssf) * gray);
    g = clamp01(ssf * g + (1.f - ssf) * gray);
    bl = clamp01(ssf * bl + (1.f - ssf) * gray);
    // rgb -> hsv
    float mx = fmaxf(r, fmaxf(g, bl));
    float mn = fminf(r, fminf(g, bl));
    float d = mx - mn;
    float dsv = (d > 0.f) ? d : 1.f;
    float hch;
    if (mx == r) {
        float t = (g - bl) / dsv;
        t = fmodf(t, 6.f);
        if (t < 0.f) t += 6.f;
        hch = t;
    } else if (mx == g) {
        hch = (bl - r) / dsv + 2.f;
    } else {
        hch = (r - g) / dsv + 4.f;
    }
    hch = (d > 0.f) ? hch * (1.f / 6.f) : 0.f;
    float sat = (mx > 0.f) ? d / mx : 0.f;
    float v = mx;
    // hue shift, mod 1
    float hh = hch + hd;
    hh -= floorf(hh);
    // hsv -> rgb
    float h6 = hh * 6.f;
    float fi = floorf(h6);
    float f = h6 - fi;
    float pp = v * (1.f - sat);
    float q = v * (1.f - f * sat);
    float t = v * (1.f - (1.f - f) * sat);
    int im = ((int)fi) % 6;
    float ro, go, bo;
    switch (im) {
        case 0: ro = v;  go = t;  bo = pp; break;
        case 1: ro = q;  go = v;  bo = pp; break;
        case 2: ro = pp; go = v;  bo = t;  break;
        case 3: ro = pp; go = q;  bo = v;  break;
        case 4: ro = t;  go = pp; bo = v;  break;
        default: ro = v; go = pp; bo = q;  break;
    }
    r = clamp01(ro); g = clamp01(go); bl = clamp01(bo);
}

__global__ void k_jitter(float* __restrict__ io, const float* __restrict__ jit,
                         const float* __restrict__ partials) {
    int b = blockIdx.y;
    int tid = threadIdx.x;

    // deterministic re-reduce of the 256 per-block partials -> mean
    float pv = partials[b * 256 + tid];
#pragma unroll
    for (int off = 32; off > 0; off >>= 1) pv += __shfl_down(pv, off, 64);
    __shared__ float ls[4];
    int wid = tid >> 6, lane = tid & 63;
    if (lane == 0) ls[wid] = pv;
    __syncthreads();
    float mean = (ls[0] + ls[1] + ls[2] + ls[3]) * (1.f / (float)OUTI_PIX);

    float cc = 0.9f + 0.2f * jit[b * 4 + 1];
    float ssf = 0.9f + 0.2f * jit[b * 4 + 2];
    float hd = -0.1f + 0.2f * jit[b * 4 + 3];

    int idx4 = blockIdx.x * blockDim.x + tid;  // 0..16383 (float4 index)
    float4* pr = (float4*)(io + (size_t)b * 3 * OUTI_PIX) + idx4;
    float4* pg = pr + OUTI_PIX / 4;
    float4* pb = pr + 2 * (OUTI_PIX / 4);
    float4 r = *pr, g = *pg, bl = *pb;

    jitter_px(r.x, g.x, bl.x, cc, ssf, hd, mean);
    jitter_px(r.y, g.y, bl.y, cc, ssf, hd, mean);
    jitter_px(r.z, g.z, bl.z, cc, ssf, hd, mean);
    jitter_px(r.w, g.w, bl.w, cc, ssf, hd, mean);

    *pr = r; *pg = g; *pb = bl;
}

extern "C" void kernel_launch(void* const* d_in, const int* in_sizes, int n_in,
                              void* d_out, int out_size, void* d_ws, size_t ws_size,
                              hipStream_t stream) {
    const float* img = (const float*)d_in[0];
    const float* ms = (const float*)d_in[1];
    const float* bg = (const float*)d_in[2];
    const int* pads = (const int*)d_in[3];
    const int* csel = (const int*)d_in[4];
    const float* rcol = (const float*)d_in[5];
    const float* jit = (const float*)d_in[6];
    float* out = (float*)d_out;

    int* bbox = (int*)d_ws;
    float* partials = (float*)((char*)d_ws + B_SAMPLES * 4 * sizeof(int));
    float* outm = out + (size_t)B_SAMPLES * 3 * OUTI_PIX;

    // init bbox to large positive for atomicMin combine
    hipMemsetAsync(bbox, 0x7F, B_SAMPLES * 4 * sizeof(int), stream);

    k_bbox<<<dim3(BBOX_CHUNKS, B_SAMPLES), 256, 0, stream>>>(ms, bbox);
    k_resize_img<<<dim3(OUTI_PIX / 256, B_SAMPLES), 256, 0, stream>>>(
        img, ms, bg, pads, csel, rcol, jit, bbox, out, partials);
    k_resize_msk<<<dim3((OUTM * OUTM) / 256, B_SAMPLES), 256, 0, stream>>>(ms, pads, bbox, outm);
    k_jitter<<<dim3(OUTI_PIX / 4 / 256, B_SAMPLES), 256, 0, stream>>>(out, jit, partials);
}

// Round 3
// 134.612 us; speedup vs baseline: 1.8665x; 1.0435x over previous
//
#include <hip/hip_runtime.h>

#define H_IN 448
#define W_IN 448
#define HW_IN (H_IN * W_IN)
#define BGW 488
#define BGHW (BGW * BGW)
#define OUTI 256
#define OUTI_PIX (OUTI * OUTI)
#define OUTM 64
#define B_SAMPLES 64
#define BBOX_CHUNKS 16
#define BBOX_ROWS (H_IN / BBOX_CHUNKS)  // 28

__device__ __forceinline__ float clamp01(float x) { return fminf(fmaxf(x, 0.f), 1.f); }
__device__ __forceinline__ int clampi(int x, int lo, int hi) { return min(max(x, lo), hi); }

// ---------------- K1: per-sample mask bounding box (split across chunks) ----------------
// bbox layout per sample: [miny, -maxy, minx, -maxx], combined via atomicMin.
// Init pattern 0x7F7F7F7F. Empty-chunk contributions equal reference identities.
__global__ void k_bbox(const float* __restrict__ ms, int* __restrict__ bbox) {
    int b = blockIdx.y;
    int chunk = blockIdx.x;
    const float4* m4 = (const float4*)(ms + (size_t)b * HW_IN + (size_t)chunk * BBOX_ROWS * W_IN);
    int miny = H_IN, maxy = -1, minx = W_IN, maxx = -1;
    const int N4 = BBOX_ROWS * (W_IN / 4);  // 3136
    for (int i = threadIdx.x; i < N4; i += blockDim.x) {
        float4 v = m4[i];
        bool a0 = v.x > 0.5f, a1 = v.y > 0.5f, a2 = v.z > 0.5f, a3 = v.w > 0.5f;
        if (a0 | a1 | a2 | a3) {
            int y = chunk * BBOX_ROWS + i / (W_IN / 4);
            int xb = (i % (W_IN / 4)) * 4;
            miny = min(miny, y); maxy = max(maxy, y);
            if (a0) { minx = min(minx, xb);     maxx = max(maxx, xb); }
            if (a1) { minx = min(minx, xb + 1); maxx = max(maxx, xb + 1); }
            if (a2) { minx = min(minx, xb + 2); maxx = max(maxx, xb + 2); }
            if (a3) { minx = min(minx, xb + 3); maxx = max(maxx, xb + 3); }
        }
    }
    __shared__ int s[4];
    if (threadIdx.x == 0) { s[0] = H_IN; s[1] = -1; s[2] = W_IN; s[3] = -1; }
    __syncthreads();
    atomicMin(&s[0], miny); atomicMax(&s[1], maxy);
    atomicMin(&s[2], minx); atomicMax(&s[3], maxx);
    __syncthreads();
    if (threadIdx.x == 0) {
        atomicMin(&bbox[b * 4 + 0], s[0]);
        atomicMin(&bbox[b * 4 + 1], -s[1]);
        atomicMin(&bbox[b * 4 + 2], s[2]);
        atomicMin(&bbox[b * 4 + 3], -s[3]);
    }
}

struct Geo {
    int miny, minx, h, w, top, left, Hp, Wp;
};
__device__ __forceinline__ Geo load_geo(const int* __restrict__ bbox,
                                        const int* __restrict__ pads, int b) {
    Geo g;
    g.miny = bbox[b * 4 + 0];
    int maxy = -bbox[b * 4 + 1];
    g.minx = bbox[b * 4 + 2];
    int maxx = -bbox[b * 4 + 3];
    int left = pads[b * 4 + 0], right = pads[b * 4 + 1];
    int top = pads[b * 4 + 2], bot = pads[b * 4 + 3];
    g.h = maxy - g.miny + 1;
    g.w = maxx - g.minx + 1;
    g.top = top; g.left = left;
    g.Hp = g.h + top + bot;
    g.Wp = g.w + left + right;
    return g;
}

__device__ __forceinline__ void src_coord(int i, int n_out, int size,
                                          int& t0, int& t1, float& frac) {
    float sizef = (float)size;
    float t = (i + 0.5f) * (sizef / (float)n_out) - 0.5f;
    t = fminf(fmaxf(t, 0.f), sizef - 1.f);
    t0 = (int)floorf(t);
    t1 = min(t0 + 1, size - 1);
    frac = t - (float)t0;
}

// ---------------- K2: row-staged bilinear resize + composite + brightness ----------------
// Block = one output row of one sample. Stage the two source rows (ms, img x3, bg x3)
// into LDS with coalesced float4 streams; compute the 4 taps from LDS.
__global__ void __launch_bounds__(256) k_resize_img(
        const float* __restrict__ img, const float* __restrict__ ms,
        const float* __restrict__ bg, const int* __restrict__ pads,
        const int* __restrict__ csel, const float* __restrict__ rcol,
        const float* __restrict__ jit, const int* __restrict__ bbox,
        float* __restrict__ out, float* __restrict__ partials) {
    int b = blockIdx.y;
    int oy = blockIdx.x;      // output row 0..255
    int tid = threadIdx.x;    // output col 0..255

    Geo g = load_geo(bbox, pads, b);
    bool useBg = csel[b] > 2;
    float c0 = rcol[b * 3 + 0], c1 = rcol[b * 3 + 1], c2 = rcol[b * 3 + 2];
    float bfac = 0.9f + 0.2f * jit[b * 4 + 0];

    int y0, y1; float wy;
    src_coord(oy, OUTI, g.Hp, y0, y1, wy);
    int r0 = clampi(g.miny + y0 - g.top, 0, H_IN - 1);
    int r1 = clampi(g.miny + y1 - g.top, 0, H_IN - 1);
    int P0 = clampi(y0, 0, BGW - 1);
    int P1 = clampi(y1, 0, BGW - 1);
    bool incy0 = (y0 >= g.top) && (y0 < g.top + g.h);
    bool incy1 = (y1 >= g.top) && (y1 < g.top + g.h);

    __shared__ float s_ms[2][W_IN];
    __shared__ float s_im[2][3][W_IN];
    __shared__ float s_bg[2][3][BGW];

    const float* msB = ms + (size_t)b * HW_IN;
    const float* imB = img + (size_t)b * 3 * HW_IN;
    const float* bgB = bg + (size_t)b * 3 * BGHW;

    // stage ms (2 rows) + img (2 rows x 3 ch): 8 planes x 112 float4
    for (int item = tid; item < 8 * (W_IN / 4); item += 256) {
        int plane = item / (W_IN / 4);
        int idx = item - plane * (W_IN / 4);
        const float* sp;
        float* dp;
        if (plane < 2) {
            sp = msB + (size_t)(plane ? r1 : r0) * W_IN;
            dp = s_ms[plane];
        } else {
            int q = plane - 2;
            int ky = q / 3, ch = q - 3 * ky;
            sp = imB + (size_t)ch * HW_IN + (size_t)(ky ? r1 : r0) * W_IN;
            dp = &s_im[ky][ch][0];
        }
        ((float4*)dp)[idx] = ((const float4*)sp)[idx];
    }
    // stage bg (2 rows x 3 ch): 6 planes x 122 float4 (only when used)
    if (useBg) {
        for (int item = tid; item < 6 * (BGW / 4); item += 256) {
            int plane = item / (BGW / 4);
            int idx = item - plane * (BGW / 4);
            int ky = plane / 3, ch = plane - 3 * ky;
            const float* sp = bgB + (size_t)ch * BGHW + (size_t)(ky ? P1 : P0) * BGW;
            ((float4*)(&s_bg[ky][ch][0]))[idx] = ((const float4*)sp)[idx];
        }
    }
    __syncthreads();

    int x0, x1; float wx;
    src_coord(tid, OUTI, g.Wp, x0, x1, wx);

    float acc0 = 0.f, acc1 = 0.f, acc2 = 0.f;
#pragma unroll
    for (int tap = 0; tap < 4; ++tap) {
        int ky = tap >> 1;
        int Q = (tap & 1) ? x1 : x0;
        float wgt = (ky ? wy : 1.f - wy) * ((tap & 1) ? wx : 1.f - wx);
        bool incy = ky ? incy1 : incy0;
        bool in_crop = incy && (Q >= g.left) && (Q < g.left + g.w);
        int c = clampi(g.minx + Q - g.left, 0, W_IN - 1);
        bool mm = in_crop && (s_ms[ky][c] > 0.5f);
        float v0, v1, v2;
        if (mm) {
            v0 = s_im[ky][0][c]; v1 = s_im[ky][1][c]; v2 = s_im[ky][2][c];
        } else if (useBg) {
            int Qc = clampi(Q, 0, BGW - 1);
            v0 = s_bg[ky][0][Qc]; v1 = s_bg[ky][1][Qc]; v2 = s_bg[ky][2][Qc];
        } else {
            v0 = c0; v1 = c1; v2 = c2;
        }
        acc0 += wgt * v0; acc1 += wgt * v1; acc2 += wgt * v2;
    }
    float o0 = clamp01(acc0 * bfac);
    float o1 = clamp01(acc1 * bfac);
    float o2 = clamp01(acc2 * bfac);
    size_t o = (size_t)b * 3 * OUTI_PIX + (size_t)oy * OUTI + tid;
    out[o] = o0;
    out[o + OUTI_PIX] = o1;
    out[o + 2 * OUTI_PIX] = o2;

    // deterministic per-row gray partial sum
    float gsum = 0.299f * o0 + 0.587f * o1 + 0.114f * o2;
#pragma unroll
    for (int off = 32; off > 0; off >>= 1) gsum += __shfl_down(gsum, off, 64);
    __shared__ float ls[4];
    int wid = tid >> 6, lane = tid & 63;
    if (lane == 0) ls[wid] = gsum;
    __syncthreads();
    if (tid == 0)
        partials[b * 256 + oy] = ls[0] + ls[1] + ls[2] + ls[3];
}

// ---------------- K2b: bilinear resize of mask to 64x64 (gather; tiny) ----------------
__global__ void k_resize_msk(const float* __restrict__ ms, const int* __restrict__ pads,
                             const int* __restrict__ bbox, float* __restrict__ outm) {
    int b = blockIdx.y;
    int pix = blockIdx.x * blockDim.x + threadIdx.x;  // 0..4095
    int oy = pix >> 6, ox = pix & 63;

    Geo g = load_geo(bbox, pads, b);
    int y0, y1, x0, x1; float wy, wx;
    src_coord(oy, OUTM, g.Hp, y0, y1, wy);
    src_coord(ox, OUTM, g.Wp, x0, x1, wx);

    const float* msB = ms + (size_t)b * HW_IN;
    float acc = 0.f;
#pragma unroll
    for (int tap = 0; tap < 4; ++tap) {
        int P = (tap & 2) ? y1 : y0;
        int Q = (tap & 1) ? x1 : x0;
        float wgt = ((tap & 2) ? wy : 1.f - wy) * ((tap & 1) ? wx : 1.f - wx);
        bool in_crop = (P >= g.top) && (P < g.top + g.h) && (Q >= g.left) && (Q < g.left + g.w);
        int r = clampi(g.miny + P - g.top, 0, H_IN - 1);
        int c = clampi(g.minx + Q - g.left, 0, W_IN - 1);
        bool mm = in_crop && (msB[r * W_IN + c] > 0.5f);
        acc += wgt * (mm ? 1.f : 0.f);
    }
    outm[(size_t)b * (OUTM * OUTM) + pix] = acc;
}

// ---------------- K3: contrast + saturation + hue jitter (in place, 4 px/thread) --------
__device__ __forceinline__ void jitter_px(float& r, float& g, float& bl,
                                          float cc, float ssf, float hd, float mean) {
    r = clamp01(cc * r + (1.f - cc) * mean);
    g = clamp01(cc * g + (1.f - cc) * mean);
    bl = clamp01(cc * bl + (1.f - cc) * mean);
    float gray = 0.299f * r + 0.587f * g + 0.114f * bl;
    r = clamp01(ssf * r + (1.f - ssf) * gray);
    g = clamp01(ssf * g + (1.f - ssf) * gray);
    bl = clamp01(ssf * bl + (1.f - ssf) * gray);
    float mx = fmaxf(r, fmaxf(g, bl));
    float mn = fminf(r, fminf(g, bl));
    float d = mx - mn;
    float dsv = (d > 0.f) ? d : 1.f;
    float hch;
    if (mx == r) {
        float t = (g - bl) / dsv;
        t = fmodf(t, 6.f);
        if (t < 0.f) t += 6.f;
        hch = t;
    } else if (mx == g) {
        hch = (bl - r) / dsv + 2.f;
    } else {
        hch = (r - g) / dsv + 4.f;
    }
    hch = (d > 0.f) ? hch * (1.f / 6.f) : 0.f;
    float sat = (mx > 0.f) ? d / mx : 0.f;
    float v = mx;
    float hh = hch + hd;
    hh -= floorf(hh);
    float h6 = hh * 6.f;
    float fi = floorf(h6);
    float f = h6 - fi;
    float pp = v * (1.f - sat);
    float q = v * (1.f - f * sat);
    float t = v * (1.f - (1.f - f) * sat);
    int im = ((int)fi) % 6;
    float ro, go, bo;
    switch (im) {
        case 0: ro = v;  go = t;  bo = pp; break;
        case 1: ro = q;  go = v;  bo = pp; break;
        case 2: ro = pp; go = v;  bo = t;  break;
        case 3: ro = pp; go = q;  bo = v;  break;
        case 4: ro = t;  go = pp; bo = v;  break;
        default: ro = v; go = pp; bo = q;  break;
    }
    r = clamp01(ro); g = clamp01(go); bl = clamp01(bo);
}

__global__ void k_jitter(float* __restrict__ io, const float* __restrict__ jit,
                         const float* __restrict__ partials) {
    int b = blockIdx.y;
    int tid = threadIdx.x;

    float pv = partials[b * 256 + tid];
#pragma unroll
    for (int off = 32; off > 0; off >>= 1) pv += __shfl_down(pv, off, 64);
    __shared__ float ls[4];
    int wid = tid >> 6, lane = tid & 63;
    if (lane == 0) ls[wid] = pv;
    __syncthreads();
    float mean = (ls[0] + ls[1] + ls[2] + ls[3]) * (1.f / (float)OUTI_PIX);

    float cc = 0.9f + 0.2f * jit[b * 4 + 1];
    float ssf = 0.9f + 0.2f * jit[b * 4 + 2];
    float hd = -0.1f + 0.2f * jit[b * 4 + 3];

    int idx4 = blockIdx.x * blockDim.x + tid;  // float4 index
    float4* pr = (float4*)(io + (size_t)b * 3 * OUTI_PIX) + idx4;
    float4* pg = pr + OUTI_PIX / 4;
    float4* pb = pr + 2 * (OUTI_PIX / 4);
    float4 r = *pr, g = *pg, bl = *pb;

    jitter_px(r.x, g.x, bl.x, cc, ssf, hd, mean);
    jitter_px(r.y, g.y, bl.y, cc, ssf, hd, mean);
    jitter_px(r.z, g.z, bl.z, cc, ssf, hd, mean);
    jitter_px(r.w, g.w, bl.w, cc, ssf, hd, mean);

    *pr = r; *pg = g; *pb = bl;
}

extern "C" void kernel_launch(void* const* d_in, const int* in_sizes, int n_in,
                              void* d_out, int out_size, void* d_ws, size_t ws_size,
                              hipStream_t stream) {
    const float* img = (const float*)d_in[0];
    const float* ms = (const float*)d_in[1];
    const float* bg = (const float*)d_in[2];
    const int* pads = (const int*)d_in[3];
    const int* csel = (const int*)d_in[4];
    const float* rcol = (const float*)d_in[5];
    const float* jit = (const float*)d_in[6];
    float* out = (float*)d_out;

    int* bbox = (int*)d_ws;
    float* partials = (float*)((char*)d_ws + B_SAMPLES * 4 * sizeof(int));
    float* outm = out + (size_t)B_SAMPLES * 3 * OUTI_PIX;

    hipMemsetAsync(bbox, 0x7F, B_SAMPLES * 4 * sizeof(int), stream);

    k_bbox<<<dim3(BBOX_CHUNKS, B_SAMPLES), 256, 0, stream>>>(ms, bbox);
    k_resize_img<<<dim3(OUTI, B_SAMPLES), 256, 0, stream>>>(
        img, ms, bg, pads, csel, rcol, jit, bbox, out, partials);
    k_resize_msk<<<dim3((OUTM * OUTM) / 256, B_SAMPLES), 256, 0, stream>>>(ms, pads, bbox, outm);
    k_jitter<<<dim3(OUTI_PIX / 4 / 256, B_SAMPLES), 256, 0, stream>>>(out, jit, partials);
}